// Round 10
// baseline (39.699 us; speedup 1.0000x reference)
//
#include <hip/hip_runtime.h>

// PS-RoI-Align (torchvision ps_roi_align semantics).
// feat: [4, 784, 112, 112] fp32; rois: [K,5]; out: [K, 16, 7, 7] fp32.
//
// R9: depth-2 pipeline with stage issued AT TOP of round (corrected R7).
//   R5-R8 post-mortem: R5/R6 (stage-at-top, depth-1) = 2.70us/plane/CU;
//   R7 (stage-at-end, depth-2) = 3.05; R8 (3 blocks/CU) = 3.0. Distinguish:
//   H1 latency-bound (need 2 planes continuously in flight, R7's defect was
//   issue placement) vs H2 DRAM-service-bound (~4.8 TB/s is the ceiling).
//   Round i:
//     stage P(i+2) -> buf[(i+2)%3]     // FIRST: keep 2 planes in flight
//     s_waitcnt vmcnt(2*cw)            // P(i) landed; P(i+1),P(i+2) in flight
//     s_barrier
//     compute P(i) from buf[i%3]
//     s_barrier                        // buf[i%3] free for round i+1's stage
//   cw = chunks/wave: wave0 owns 7 (chunks w,w+8,..,48), waves1-7 own 6.
//   256 blocks x 512 thr, 3 x 50KB LDS. If neutral -> R5 is the roofline.

#define PP 7
#define SR 2
#define SCALEF 0.0625f

constexpr int Cc     = 784;            // Cout * P * P
constexpr int Hh     = 112;
constexpr int Ww     = 112;
constexpr int PLANE  = Hh * Ww;        // 12544 floats = 50176 B
constexpr int CHUNKS = 49;             // 1KB chunks (64 lanes x 16 B)
constexpr int NBLK   = 256;            // 1 block / CU
constexpr int TPB    = 512;            // 8 waves
constexpr int RPT    = 2;              // rois per thread (K <= 1024)

__global__ __launch_bounds__(TPB) void psroi_persist_kernel(
    const float* __restrict__ feat,
    const float* __restrict__ rois,
    float* __restrict__ out,
    int K, int nplanes)
{
    __shared__ float buf[3][PLANE];    // 150528 B <= 160 KB

    int tid  = threadIdx.x;
    int wave = tid >> 6;
    int lane = tid & 63;

    // ---- parse roi params once per block into registers ----
    int   rb[RPT];
    float x1[RPT], y1[RPT], bsh[RPT], bsw[RPT];
#pragma unroll
    for (int j = 0; j < RPT; ++j) {
        int k = tid + j * TPB;
        if (k < K) {
            const float* r = rois + (size_t)k * 5;
            rb[j]  = (int)r[0];
            x1[j]  = r[1] * SCALEF - 0.5f;
            y1[j]  = r[2] * SCALEF - 0.5f;
            float rw = fmaxf(r[3] * SCALEF - 0.5f - x1[j], 0.1f);
            float rh = fmaxf(r[4] * SCALEF - 0.5f - y1[j], 0.1f);
            bsh[j] = rh * (1.0f / (float)PP);
            bsw[j] = rw * (1.0f / (float)PP);
        } else {
            rb[j] = -1;
        }
    }

    // ---- async stage one plane into buf[bi]; wave w owns chunks w, w+8, ... ----
    auto stage = [&](int bi, int p) {
        const float* src = feat + (size_t)p * PLANE;
        for (int j = wave; j < CHUNKS; j += TPB / 64) {
            __builtin_amdgcn_global_load_lds(
                (const __attribute__((address_space(1))) void*)(src + j * 256 + lane * 4),
                (__attribute__((address_space(3))) void*)(&buf[bi][j * 256]),
                16, 0, 0);
        }
    };

    // balanced contiguous partition: blocks 0..63 get 13 planes, rest 12
    int per   = nplanes / NBLK;
    int rem   = nplanes % NBLK;
    int bid   = blockIdx.x;
    int start = bid * per + min(bid, rem);
    int cnt   = per + (bid < rem ? 1 : 0);

    stage(0, start);                       // pipeline fill
    if (cnt > 1) stage(1, start + 1);

    for (int i = 0; i < cnt; ++i) {
        int p = start + i;

        if (i + 2 < cnt) {
            stage((i + 2) % 3, p + 2);     // keep 2 planes in flight, issued FIRST
            // wait: P(i) done, P(i+1)+P(i+2) (2*cw) may remain outstanding
            if (wave == 0) asm volatile("s_waitcnt vmcnt(14)" ::: "memory");
            else           asm volatile("s_waitcnt vmcnt(12)" ::: "memory");
        } else if (i + 1 < cnt) {
            if (wave == 0) asm volatile("s_waitcnt vmcnt(7)" ::: "memory");
            else           asm volatile("s_waitcnt vmcnt(6)" ::: "memory");
        } else {
            asm volatile("s_waitcnt vmcnt(0)" ::: "memory");
        }
        __builtin_amdgcn_s_barrier();      // buf[i%3] fully landed for all waves

        int b  = p / Cc;
        int c  = p % Cc;
        int pw = c % PP;
        int ph = (c % (PP * PP)) / PP;
        const float* pl = buf[i % 3];

#pragma unroll
        for (int j = 0; j < RPT; ++j) {
            if (rb[j] != b) continue;
            float acc = 0.0f;
#pragma unroll
            for (int iy = 0; iy < SR; ++iy) {
                float gy = ((float)iy + 0.5f) / (float)SR;
                float y  = y1[j] + ((float)ph + gy) * bsh[j];
                bool  vy = (y >= -1.0f) && (y <= (float)Hh);
                float yc = fminf(fmaxf(y, 0.0f), (float)(Hh - 1));
                int   yl = (int)yc;            // yc >= 0 -> trunc == floor
                int   yh = min(yl + 1, Hh - 1);
                float ly = yc - (float)yl;
                float hy = 1.0f - ly;
#pragma unroll
                for (int ix = 0; ix < SR; ++ix) {
                    float gx = ((float)ix + 0.5f) / (float)SR;
                    float x  = x1[j] + ((float)pw + gx) * bsw[j];
                    bool  vx = (x >= -1.0f) && (x <= (float)Ww);
                    float xc = fminf(fmaxf(x, 0.0f), (float)(Ww - 1));
                    int   xl = (int)xc;
                    int   xh = min(xl + 1, Ww - 1);
                    float lx = xc - (float)xl;
                    float hx = 1.0f - lx;

                    float v = hy * hx * pl[yl * Ww + xl]
                            + hy * lx * pl[yl * Ww + xh]
                            + ly * hx * pl[yh * Ww + xl]
                            + ly * lx * pl[yh * Ww + xh];
                    acc += (vy && vx) ? v : 0.0f;
                }
            }
            int k = tid + j * TPB;
            out[(size_t)k * Cc + c] = acc * (1.0f / (float)(SR * SR));
        }

        asm volatile("" ::: "memory");
        __builtin_amdgcn_s_barrier();      // all waves done with buf[i%3]
    }
}

extern "C" void kernel_launch(void* const* d_in, const int* in_sizes, int n_in,
                              void* d_out, int out_size, void* d_ws, size_t ws_size,
                              hipStream_t stream) {
    const float* feat = (const float*)d_in[0];
    const float* rois = (const float*)d_in[1];
    float* out = (float*)d_out;

    int K = in_sizes[1] / 5;
    int nplanes = in_sizes[0] / PLANE;          // N * Cc = 3136
    psroi_persist_kernel<<<NBLK, TPB, 0, stream>>>(feat, rois, out, K, nplanes);
}